// Round 4
// baseline (269.051 us; speedup 1.0000x reference)
//
#include <hip/hip_runtime.h>

// RoiAlign (TF crop_and_resize style), fp32, NHWC.
// features: [B,H,W,C] = [2,64,64,256]; rois: [B,N,4] = [2,2000,4]
// out: [B,N,7,7,C]
//
// R5: sorted-order consumption ("sliding y-window").
// History: R2 direct gather kernel ~91us (dur 216 incl ~125us harness
// fill). R3 XCD y-banding ~103us (blockIdx%8->XCD mapping assumption
// false). R4 LDS binning ~120us (8x staging redundancy, 1 block/CU).
// Theory: R2 moves 784MB reads + 200MB nt writes in 91us = 10.8 TB/s
// combined -> reads are L3-served (concurrent working set = all 8MB of
// both images -> L2 thrash at 2x capacity). Fix the working set by TIME,
// not placement: counting-sort rows by (b,y0), consume in global sorted
// order with static chunking (chunk = blockIdx). Blocks dispatch roughly
// in blockIdx order, so resident waves always span a narrow y-band;
// every XCD's L2 caches the same sliding ~1.2MB window (residency capped
// at 4 blocks/CU via 40KB LDS pad -> ~4096 resident rows ~ 19 y-rows).
// Consume inner loop is bit-identical to R2. Sort affects ORDER only, so
// correctness does not depend on FP agreement between passes.
// Fallback to the proven R2 kernel if ws_size < ~7.2 MB.

#define POOL  7
#define NBINS 128          // 2 batches * 64 y0 values

typedef float vfloat4 __attribute__((ext_vector_type(4)));

// ---------- pass 0: zero bin counters ----------
__global__ void zero_counts(int* __restrict__ counts) {
    if ((int)threadIdx.x < NBINS) counts[threadIdx.x] = 0;
}

// ---------- pass 1: bin output rows by (batch, y0) ----------
__global__ __launch_bounds__(256) void bin_rows(
    const float* __restrict__ rois,
    int* __restrict__ counts,
    int* __restrict__ slots,
    int H, int N, int CAP)
{
    const int rows_per_batch = N * POOL;
    const int total = 2 * rows_per_batch;
    const int gid = blockIdx.x * 256 + threadIdx.x;
    if (gid >= total) return;

    const int b   = gid / rows_per_batch;
    const int rem = gid - b * rows_per_batch;      // n*POOL + py
    const int n   = rem / POOL;
    const int py  = rem - n * POOL;

    const float* r = rois + ((long long)b * N + n) * 4;
    const float ry1 = r[0], ry2 = r[2];

    const float fy  = (float)py * (1.0f / (POOL - 1));
    const float ys  = (ry1 + fy * (ry2 - ry1)) * (float)(H - 1);
    const float y0f = fminf(fmaxf(floorf(ys), 0.0f), (float)(H - 1));
    const int   y0  = (int)y0f;

    const int bin = b * 64 + y0;
    const int idx = atomicAdd(&counts[bin], 1);    // idx < CAP by construction
    slots[bin * CAP + idx] = rem;
}

// ---------- pass 1.5: exclusive prefix over 128 bins ----------
__global__ void prefix_scan(const int* __restrict__ counts,
                            int* __restrict__ offsets) {
    __shared__ int tmp[NBINS];
    const int t = threadIdx.x;                     // 128 threads
    tmp[t] = counts[t];
    __syncthreads();
    for (int d = 1; d < NBINS; d <<= 1) {
        const int v = (t >= d) ? tmp[t - d] : 0;
        __syncthreads();
        tmp[t] += v;
        __syncthreads();
    }
    offsets[t + 1] = tmp[t];                       // inclusive -> shifted
    if (t == 0) offsets[0] = 0;
}

// ---------- pass 2: consume rows in sorted (b,y0) order ----------
__global__ __launch_bounds__(256) void roialign_sorted(
    const float* __restrict__ feat,   // [B,H,W,C]
    const float* __restrict__ rois,   // [B,N,4]
    float* __restrict__ out,          // [B,N,POOL,POOL,C]
    const int* __restrict__ offsets,  // [NBINS+1]
    const int* __restrict__ slots,    // [NBINS][CAP]
    int H, int W, int C4, int N, int CAP, int total)
{
    // 40 KB LDS pad: caps residency at 4 blocks/CU (160/40) so the
    // concurrently-processed sorted window stays ~1.2 MB (L2-resident).
    __shared__ int occ_pad[10240];
    if (H == 0) ((volatile int*)occ_pad)[threadIdx.x] = 1;  // keep-alive, never taken

    const int lane = threadIdx.x & 63;
    const int wid  = threadIdx.x >> 6;             // wave 0..3
    const int gid  = blockIdx.x * 4 + wid;         // sorted row index
    if (gid >= total) return;

    // binary search: bin s.t. offsets[bin] <= gid < offsets[bin+1]
    int lo = 0, hi = NBINS;
    while (hi - lo > 1) {
        const int mid = (lo + hi) >> 1;
        if (offsets[mid] <= gid) lo = mid; else hi = mid;
    }
    const int bin = lo;
    const int rem = slots[bin * CAP + (gid - offsets[lo])];  // wave-uniform
    const int b   = bin >> 6;

    const int n  = rem / POOL;
    const int py = rem - n * POOL;

    const float* r = rois + ((long long)b * N + n) * 4;
    const float ry1 = r[0], rx1 = r[1], ry2 = r[2], rx2 = r[3];

    const float fy  = (float)py * (1.0f / (POOL - 1));
    const float ys  = (ry1 + fy * (ry2 - ry1)) * (float)(H - 1);
    const float y0f = fminf(fmaxf(floorf(ys), 0.0f), (float)(H - 1));
    const int   y0  = (int)y0f;
    const int   y1i = min(y0 + 1, H - 1);
    const float wy  = ys - y0f;

    const vfloat4* fb = (const vfloat4*)feat + (long long)b * H * W * C4;
    const vfloat4* r0 = fb + (long long)y0  * W * C4 + lane;
    const vfloat4* r1 = fb + (long long)y1i * W * C4 + lane;

    vfloat4* ob = (vfloat4*)out +
        (((long long)b * N + n) * (POOL * POOL) + (long long)py * POOL) * C4 + lane;

    const float dx = rx2 - rx1;

#pragma unroll
    for (int px = 0; px < POOL; ++px) {
        const float fx  = (float)px * (1.0f / (POOL - 1));
        const float xs  = (rx1 + fx * dx) * (float)(W - 1);
        const float x0f = fminf(fmaxf(floorf(xs), 0.0f), (float)(W - 1));
        const int   x0  = (int)x0f;
        const int   x1i = min(x0 + 1, W - 1);
        const float wx  = xs - x0f;

        const vfloat4 f00 = r0[x0  * C4];
        const vfloat4 f01 = r0[x1i * C4];
        const vfloat4 f10 = r1[x0  * C4];
        const vfloat4 f11 = r1[x1i * C4];

        const vfloat4 top = f00 + (f01 - f00) * wx;
        const vfloat4 bot = f10 + (f11 - f10) * wx;
        const vfloat4 o   = top + (bot - top) * wy;

        __builtin_nontemporal_store(o, ob + px * C4);
    }
}

// ---------- fallback: proven direct kernel (R2 structure, ~91 us) ----------
__global__ __launch_bounds__(256) void roialign_direct(
    const float* __restrict__ feat, const float* __restrict__ rois,
    float* __restrict__ out, int H, int W, int C4, int N, int blocks_per_batch)
{
    const int lane = threadIdx.x & 63;
    const int wid  = threadIdx.x >> 6;
    const int xcd  = blockIdx.x & 7;
    const int slot = blockIdx.x >> 3;
    const int b    = xcd >> 2;
    const int lblock = slot * 4 + (xcd & 3);
    if (lblock >= blocks_per_batch) return;
    const int row = lblock * 4 + wid;
    if (row >= N * POOL) return;
    const int n  = row / POOL;
    const int py = row - n * POOL;

    const float* r = rois + ((long long)b * N + n) * 4;
    const float ry1 = r[0], rx1 = r[1], ry2 = r[2], rx2 = r[3];
    const float fy  = (float)py * (1.0f / (POOL - 1));
    const float ys  = (ry1 + fy * (ry2 - ry1)) * (float)(H - 1);
    const float y0f = fminf(fmaxf(floorf(ys), 0.0f), (float)(H - 1));
    const int   y0  = (int)y0f;
    const int   y1i = min(y0 + 1, H - 1);
    const float wy  = ys - y0f;

    const vfloat4* fb = (const vfloat4*)feat + (long long)b * H * W * C4;
    const vfloat4* r0 = fb + (long long)y0  * W * C4 + lane;
    const vfloat4* r1 = fb + (long long)y1i * W * C4 + lane;
    vfloat4* ob = (vfloat4*)out +
        (((long long)b * N + n) * (POOL * POOL) + (long long)py * POOL) * C4 + lane;
    const float dx = rx2 - rx1;
#pragma unroll
    for (int px = 0; px < POOL; ++px) {
        const float fx  = (float)px * (1.0f / (POOL - 1));
        const float xs  = (rx1 + fx * dx) * (float)(W - 1);
        const float x0f = fminf(fmaxf(floorf(xs), 0.0f), (float)(W - 1));
        const int   x0  = (int)x0f;
        const int   x1i = min(x0 + 1, W - 1);
        const float wx  = xs - x0f;
        const vfloat4 f00 = r0[x0  * C4];
        const vfloat4 f01 = r0[x1i * C4];
        const vfloat4 f10 = r1[x0  * C4];
        const vfloat4 f11 = r1[x1i * C4];
        const vfloat4 top = f00 + (f01 - f00) * wx;
        const vfloat4 bot = f10 + (f11 - f10) * wx;
        const vfloat4 o   = top + (bot - top) * wy;
        __builtin_nontemporal_store(o, ob + px * C4);
    }
}

extern "C" void kernel_launch(void* const* d_in, const int* in_sizes, int n_in,
                              void* d_out, int out_size, void* d_ws, size_t ws_size,
                              hipStream_t stream) {
    const int B = 2, H = 64, W = 64, C = 256;
    const int N = in_sizes[1] / (B * 4);   // rois flat = B*N*4

    const float* feat = (const float*)d_in[0];
    const float* rois = (const float*)d_in[1];
    float* out = (float*)d_out;

    const int rows_per_batch = N * POOL;               // 14000
    const int CAP   = rows_per_batch;                  // hard per-bin bound
    const int total = B * rows_per_batch;              // 28000

    const size_t ws_needed = 512 * 4                   // counts[128]+offsets[129]+pad
                           + (size_t)NBINS * CAP * 4;  // slots (~7.17 MB)

    if (ws_size >= ws_needed && d_ws != nullptr) {
        int* counts  = (int*)d_ws;          // [0,128)
        int* offsets = counts + 128;        // [128,257)
        int* slots   = counts + 512;        // aligned start

        const int bin_blocks = (total + 255) / 256;    // 110
        const int con_blocks = (total + 3) / 4;        // 7000

        zero_counts<<<1, NBINS, 0, stream>>>(counts);
        bin_rows<<<bin_blocks, 256, 0, stream>>>(rois, counts, slots, H, N, CAP);
        prefix_scan<<<1, NBINS, 0, stream>>>(counts, offsets);
        roialign_sorted<<<con_blocks, 256, 0, stream>>>(
            feat, rois, out, offsets, slots, H, W, C / 4, N, CAP, total);
    } else {
        const int blocks_per_batch = (rows_per_batch + 3) / 4;
        const int slots_g = (blocks_per_batch + 3) / 4;
        roialign_direct<<<slots_g * 8, 256, 0, stream>>>(
            feat, rois, out, H, W, C / 4, N, blocks_per_batch);
    }
}